// Round 5
// baseline (138.715 us; speedup 1.0000x reference)
//
#include <hip/hip_runtime.h>

#define POOLED 7
#define SCALE  0.25f
#define CCH    256
#define HH     128
#define WW     128
#define HW     (HH * WW)

#define NCH      16                    // channels per chunk
#define NCHUNK   4                     // chunks per block -> 64 channels/block
#define NBLK_PER_BOX (CCH / (NCH * NCHUNK))  // 4 blocks per box
#define PATCH_H  15                    // row span <= 15
#define NV       5                     // float4 col-groups loaded per row (20 floats)
#define PIXROW   19                    // cols stored per row: rc 0..18 (max needed 17)
#define NPIX     (PATCH_H * PIXROW)    // 285 pixel slots
#define CHPAD    20                    // channel stride: 16 + 4 pad (16B-aligned reads)
#define ROWSTR   (PIXROW * CHPAD)      // 380 dwords per patch row

// Pixel-major LDS patch: patch[pix*CHPAD + ch], pix = ry*19 + rx (rx rel to 4-aligned
// xlo4). 22800 B. Staging: one float4/lane, scatter 4 ds_write_b32; the v=4 group
// stores only .x/.y/.z (rc 19 would alias next row). Write banks <=3-way; reads
// ds_read_b128 at 80*pix + 16*cg bytes, 16B-aligned.
// 4-deep chunk pipeline: [write u -> LDS] [issue loads chunk c+1] [barrier]
// [compute c] [barrier] ... — per-box setup (box load + precompute) amortized over
// 64 channels; one prefetch always in flight across chunk boundaries.
// NOTE: plain __launch_bounds__(256). A (256,7) min-waves variant made the allocator
// spill the prefetch regs to scratch (WRITE_SIZE 49->236 MB, 2.4x dur). Tripwire:
// WRITE_SIZE must stay ~= output size (49 MB).
__global__ __launch_bounds__(256) void roi_align_kernel(
    const float* __restrict__ feat,   // [B, C, H, W]
    const float* __restrict__ boxes,  // [K, 5]
    float* __restrict__ out,          // [K, C, 7, 7]
    int K)
{
    __shared__ __align__(16) float patch[NPIX * CHPAD];   // 22800 B

    int bx = blockIdx.x;
    int k  = bx >> 2;
    int cb = (bx & 3) * (NCH * NCHUNK);     // channel base: 0..192 step 64
    if (k >= K) return;
    int t = threadIdx.x;

    const float* box = boxes + k * 5;
    int   b  = (int)box[0];
    float x1 = box[1] * SCALE;
    float y1 = box[2] * SCALE;
    float x2 = box[3] * SCALE;
    float y2 = box[4] * SCALE;

    float roi_w = fmaxf(x2 - x1, 1.0f);
    float roi_h = fmaxf(y2 - y1, 1.0f);
    float bin_w = roi_w * (1.0f / POOLED);
    float bin_h = roi_h * (1.0f / POOLED);
    int gw = (int)ceilf(roi_w * (1.0f / POOLED));
    int gh = (int)ceilf(roi_h * (1.0f / POOLED));
    float inv_gh = 1.0f / (float)gh;
    float inv_gw = 1.0f / (float)gw;

    // ---- patch bounds (same fp expressions as per-sample coords) ----
    float ymin = y1 + 0.5f * bin_h * inv_gh;
    float ymax = y1 + 6 * bin_h + ((gh - 1) + 0.5f) * bin_h * inv_gh;
    float xmin = x1 + 0.5f * bin_w * inv_gw;

    int ylo = min((int)fmaxf(ymin, 0.0f), HH - 1);
    int xlo = min((int)fmaxf(xmin, 0.0f), WW - 1);
    int xlo4 = xlo & ~3;               // 16B-aligned patch origin
    int ylmax = min((int)fmaxf(ymax, 0.0f), HH - 1);
    int h_p = min(ylmax + 1, HH - 1) - ylo + 1;   // rows staged, <= 15
    if (h_p > PATCH_H) h_p = PATCH_H;
    // max rel col any sample references: xh <= xlo+14 -> rel <= shift+14 <= 17
    int mcr = min(WW - 1 - xlo4, (xlo - xlo4) + 14);

    // ---- block-uniform ints -> SGPRs (cheapens all downstream addr math) ----
    int s_b   = __builtin_amdgcn_readfirstlane(b);
    int s_ylo = __builtin_amdgcn_readfirstlane(ylo);
    int s_x4  = __builtin_amdgcn_readfirstlane(xlo4);
    int s_hp  = __builtin_amdgcn_readfirstlane(h_p);
    int s_mcr = __builtin_amdgcn_readfirstlane(mcr);
    int s_ns  = __builtin_amdgcn_readfirstlane(gh * gw);
    int ghm   = __builtin_amdgcn_readfirstlane(gh - 1);   // 0 or 1

    // ---- separable per-thread sample precompute ----
    int p  = t & 63;
    int pc = min(p, 48);
    int pw = pc % POOLED;
    int ph = pc / POOLED;
    int cg = t >> 6;                   // wave id = 4-channel group within chunk

    float yb = y1 + ph * bin_h;
    float xb = x1 + pw * bin_w;

    float hy0, ly0, hy1, ly1;          // validity-folded axis weights
    int   ryT0, ryhT0, ryT1, ryhT1;    // dword offsets ry*ROWSTR
    float hx0, lx0, hx1, lx1;
    int   rxT0, rxhT0, rxT1, rxhT1;    // dword offsets rx*CHPAD

#define YSIDE(IYC, HY, LY, RT, RHT) {                                   \
        float y = yb + IYC * bin_h * inv_gh;                            \
        bool vld = (y >= -1.0f) && (y <= (float)HH);                    \
        float yc = fmaxf(y, 0.0f);                                      \
        int yl = min((int)yc, HH - 1);                                  \
        int yh2 = min(yl + 1, HH - 1);                                  \
        float ly = (yl >= HH - 1) ? 0.0f : (yc - (float)yl);            \
        HY = vld ? (1.0f - ly) : 0.0f;                                  \
        LY = vld ? ly : 0.0f;                                           \
        int ry  = max(0, min(yl  - s_ylo, s_hp - 1));                   \
        int ryh = max(0, min(yh2 - s_ylo, s_hp - 1));                   \
        RT  = ry  * ROWSTR;                                             \
        RHT = ryh * ROWSTR;                                             \
    }
#define XSIDE(IXC, HX, LX, RT, RHT) {                                   \
        float x = xb + IXC * bin_w * inv_gw;                            \
        bool vld = (x >= -1.0f) && (x <= (float)WW);                    \
        float xc = fmaxf(x, 0.0f);                                      \
        int xl = min((int)xc, WW - 1);                                  \
        int xh2 = min(xl + 1, WW - 1);                                  \
        float lx = (xl >= WW - 1) ? 0.0f : (xc - (float)xl);            \
        HX = vld ? (1.0f - lx) : 0.0f;                                  \
        LX = vld ? lx : 0.0f;                                           \
        int rxl = max(0, min(xl  - s_x4, PIXROW - 1));                  \
        int rxh = max(0, min(xh2 - s_x4, PIXROW - 1));                  \
        RT  = rxl * CHPAD;                                              \
        RHT = rxh * CHPAD;                                              \
    }
    YSIDE(0.5f, hy0, ly0, ryT0, ryhT0)
    YSIDE(1.5f, hy1, ly1, ryT1, ryhT1)   // read only when gh==2
    XSIDE(0.5f, hx0, lx0, rxT0, rxhT0)
    XSIDE(1.5f, hx1, lx1, rxT1, rxhT1)   // read only when gw==2
#undef YSIDE
#undef XSIDE

    // combine into static sample slots; s enumerates (iy fastest): iy=s%gh, ix=s/gh
    float wa[4], wb[4], wc_[4], wd[4];
    int   oa[4], ob[4], oc[4], od[4];
    // s=0: (0,0)
    wa[0] = hy0 * hx0; wb[0] = hy0 * lx0; wc_[0] = ly0 * hx0; wd[0] = ly0 * lx0;
    oa[0] = ryT0 + rxT0;  ob[0] = ryT0 + rxhT0;
    oc[0] = ryhT0 + rxT0; od[0] = ryhT0 + rxhT0;
    // s=1: (iy,ix) = (ghm, 1-ghm) -> selects
    {
        float hyS = ghm ? hy1 : hy0, lyS = ghm ? ly1 : ly0;
        int ryS = ghm ? ryT1 : ryT0, ryhS = ghm ? ryhT1 : ryhT0;
        float hxS = ghm ? hx0 : hx1, lxS = ghm ? lx0 : lx1;
        int rxS = ghm ? rxT0 : rxT1, rxhS = ghm ? rxhT0 : rxhT1;
        wa[1] = hyS * hxS; wb[1] = hyS * lxS; wc_[1] = lyS * hxS; wd[1] = lyS * lxS;
        oa[1] = ryS + rxS;  ob[1] = ryS + rxhS;
        oc[1] = ryhS + rxS; od[1] = ryhS + rxhS;
    }
    // s=2: (0,1)   (s>=2 implies gh=gw=2)
    wa[2] = hy0 * hx1; wb[2] = hy0 * lx1; wc_[2] = ly0 * hx1; wd[2] = ly0 * lx1;
    oa[2] = ryT0 + rxT1;  ob[2] = ryT0 + rxhT1;
    oc[2] = ryhT0 + rxT1; od[2] = ryhT0 + rxhT1;
    // s=3: (1,1)
    wa[3] = hy1 * hx1; wb[3] = hy1 * lx1; wc_[3] = ly1 * hx1; wd[3] = ly1 * lx1;
    oa[3] = ryT1 + rxT1;  ob[3] = ryT1 + rxhT1;
    oc[3] = ryhT1 + rxT1; od[3] = ryhT1 + rxhT1;

    // ---- staging mapping: one float4 per (lch, row, col-group) slot ----
    int lch = t >> 4;                  // 0..15 channel within chunk
    int sub = t & 15;
    int lim = s_hp * NV;
    const float* gch = feat + (s_b * CCH + cb + lch) * HW;   // chunk-0 channel plane

    bool act[NV], actw[NV];
    int  goff[NV];                     // float offset within channel plane
    int  la[NV];                       // LDS float index of col j=0
#pragma unroll
    for (int i = 0; i < NV; ++i) {
        int idx = i * 16 + sub;        // 0..79, each (r,v) pair exactly once
        int r = idx / NV;
        int v = idx - r * NV;
        act[i]  = (idx < lim) && (4 * v <= s_mcr);
        actw[i] = act[i] && (v < 4);   // rc 19 would alias next row -> skip .w on v=4
        goff[i] = (s_ylo + r) * WW + min(s_x4 + 4 * v, WW - 4);
        la[i]   = (r * PIXROW + 4 * v) * CHPAD + lch;
    }

    float sc = inv_gh * inv_gw;

#define BILIN(S) {                                                      \
        float4 va = *(const float4*)(cp + oa[S]);                       \
        float4 vb = *(const float4*)(cp + ob[S]);                       \
        float4 vc = *(const float4*)(cp + oc[S]);                       \
        float4 vd = *(const float4*)(cp + od[S]);                       \
        float w1 = wa[S], w2 = wb[S], w3 = wc_[S], w4 = wd[S];          \
        acc.x += w1 * va.x + w2 * vb.x + w3 * vc.x + w4 * vd.x;         \
        acc.y += w1 * va.y + w2 * vb.y + w3 * vc.y + w4 * vd.y;         \
        acc.z += w1 * va.z + w2 * vb.z + w3 * vc.z + w4 * vd.z;         \
        acc.w += w1 * va.w + w2 * vb.w + w3 * vc.w + w4 * vd.w;         \
    }
#define COMPUTE(CHB) {                                                  \
        float4 acc = {0.0f, 0.0f, 0.0f, 0.0f};                          \
        const float* cp = patch + cg * 4;                               \
        BILIN(0)                                                        \
        if (s_ns > 1) BILIN(1)                                          \
        if (s_ns > 2) { BILIN(2) BILIN(3) }                             \
        int ob_ = (k * CCH + cb + (CHB) + cg * 4) * 49 + p;             \
        out[ob_]          = acc.x * sc;                                 \
        out[ob_ + 49]     = acc.y * sc;                                 \
        out[ob_ + 2 * 49] = acc.z * sc;                                 \
        out[ob_ + 3 * 49] = acc.w * sc;                                 \
    }

    // ---- issue chunk-0 loads ----
    float4 u[NV];
#pragma unroll
    for (int i = 0; i < NV; ++i)
        if (act[i]) u[i] = *(const float4*)(gch + goff[i]);

    // ---- 4-deep chunk pipeline ----
#pragma unroll
    for (int c = 0; c < NCHUNK; ++c) {
        if (c > 0) __syncthreads();    // WAR: prev compute done before overwrite

        // write chunk c (compiler inserts vmcnt wait on u here)
#pragma unroll
        for (int i = 0; i < NV; ++i)
            if (act[i]) {
                float* lp = patch + la[i];
                lp[0]         = u[i].x;
                lp[CHPAD]     = u[i].y;
                lp[2 * CHPAD] = u[i].z;
                if (actw[i]) lp[3 * CHPAD] = u[i].w;
            }

        // issue chunk c+1 loads; latency hides under compute c
        if (c + 1 < NCHUNK) {
            const float* gn = gch + (c + 1) * (NCH * HW);
#pragma unroll
            for (int i = 0; i < NV; ++i)
                if (act[i]) u[i] = *(const float4*)(gn + goff[i]);
        }

        __syncthreads();

        if (p < 49) COMPUTE(c * NCH)
    }
}

extern "C" void kernel_launch(void* const* d_in, const int* in_sizes, int n_in,
                              void* d_out, int out_size, void* d_ws, size_t ws_size,
                              hipStream_t stream) {
    const float* feat  = (const float*)d_in[0];
    const float* boxes = (const float*)d_in[1];
    float* out = (float*)d_out;

    int K = in_sizes[1] / 5;
    int blocks = K * NBLK_PER_BOX;     // (box, 64-channel group)
    roi_align_kernel<<<blocks, 256, 0, stream>>>(feat, boxes, out, K);
}

// Round 6
// 128.046 us; speedup vs baseline: 1.0833x; 1.0833x over previous
//
#include <hip/hip_runtime.h>

#define POOLED 7
#define SCALE  0.25f
#define CCH    256
#define HH     128
#define WW     128
#define HW     (HH * WW)

#define NCH      16                    // channels per chunk
#define NCHUNK   2                     // chunks per block -> 32 channels/block
#define NBLK_PER_BOX (CCH / (NCH * NCHUNK))  // 8 blocks per box
#define PATCH_H  15                    // row span <= 15
#define NV       5                     // float4 col-groups loaded per row (20 floats)
#define PIXROW   19                    // cols stored per row: rc 0..18 (max needed 17)
#define NPIX     (PATCH_H * PIXROW)    // 285 pixel slots
#define CHPAD    20                    // channel stride: 16 + 4 pad (16B-aligned reads)
#define ROWSTR   (PIXROW * CHPAD)      // 380 dwords per patch row

// ---------------------------------------------------------------------------
// Box-order sort: 16-bucket counting sort by (batch, y-quadrant, x-quadrant).
// Any bijective permutation is CORRECT (each box's work/output is independent);
// the perm only improves L2 locality: consecutive blocks -> same image quadrant
// -> per-XCD channel-slice working set ~0.5-2 MB (fits 4 MB L2). Without it,
// random batch order makes each XCD juggle 32ch x 4 images = 8 MB (thrash).
// Evidence: NCHUNK=4 broke slice<->XCD affinity, FETCH +39 MB <-> +11 us (1:1).
// ---------------------------------------------------------------------------
__global__ void box_sort_kernel(const float* __restrict__ boxes,
                                int* __restrict__ perm, int K)
{
    __shared__ int hist[16];
    __shared__ int base[16];
    int t = threadIdx.x;
    if (t < 16) hist[t] = 0;
    __syncthreads();
    for (int i = t; i < K; i += blockDim.x) {
        const float* bp = boxes + i * 5;
        int key = (((int)bp[0] & 3) << 2)
                | ((bp[2] >= 256.0f) ? 2 : 0)
                | ((bp[1] >= 256.0f) ? 1 : 0);
        atomicAdd(&hist[key], 1);
    }
    __syncthreads();
    if (t == 0) {
        int acc = 0;
        for (int j = 0; j < 16; ++j) { base[j] = acc; acc += hist[j]; }
    }
    __syncthreads();
    for (int i = t; i < K; i += blockDim.x) {
        const float* bp = boxes + i * 5;
        int key = (((int)bp[0] & 3) << 2)
                | ((bp[2] >= 256.0f) ? 2 : 0)
                | ((bp[1] >= 256.0f) ? 1 : 0);
        int pos = atomicAdd(&base[key], 1);
        perm[pos] = i;
    }
}

// Pixel-major LDS patch: patch[pix*CHPAD + ch], pix = ry*19 + rx (rx rel to 4-aligned
// xlo4). 22800 B -> 7 blocks/CU by LDS. Staging: one float4/lane, scatter 4
// ds_write_b32; the v=4 group stores only .x/.y/.z (rc 19 would alias next row).
// Write banks <=3-way; reads ds_read_b128 at 80*pix + 16*cg bytes, 16B-aligned.
// NOTE: plain __launch_bounds__(256). A (256,7) min-waves variant made the allocator
// spill the prefetch regs to scratch (WRITE_SIZE 49->236 MB, 2.4x dur). Tripwire:
// WRITE_SIZE must stay ~= output size (49 MB).
// NOTE: NCHUNK must stay 2 (8 blocks/box): bx%8 channel-slice <-> XCD affinity.
// NCHUNK=4 cost +39 MB FETCH / +11 us (round-5 measurement).
__global__ __launch_bounds__(256) void roi_align_kernel(
    const float* __restrict__ feat,   // [B, C, H, W]
    const float* __restrict__ boxes,  // [K, 5]
    float* __restrict__ out,          // [K, C, 7, 7]
    const int* __restrict__ perm,     // box processing order (or nullptr)
    int K)
{
    __shared__ __align__(16) float patch[NPIX * CHPAD];   // 22800 B

    int bx = blockIdx.x;
    int kq = bx >> 3;
    int cb = (bx & 7) * (NCH * NCHUNK);     // channel base: 0..224 step 32
    if (kq >= K) return;
    int k = perm ? perm[kq] : kq;
    int t = threadIdx.x;

    const float* box = boxes + k * 5;
    int   b  = (int)box[0];
    float x1 = box[1] * SCALE;
    float y1 = box[2] * SCALE;
    float x2 = box[3] * SCALE;
    float y2 = box[4] * SCALE;

    float roi_w = fmaxf(x2 - x1, 1.0f);
    float roi_h = fmaxf(y2 - y1, 1.0f);
    float bin_w = roi_w * (1.0f / POOLED);
    float bin_h = roi_h * (1.0f / POOLED);
    int gw = (int)ceilf(roi_w * (1.0f / POOLED));
    int gh = (int)ceilf(roi_h * (1.0f / POOLED));
    float inv_gh = 1.0f / (float)gh;
    float inv_gw = 1.0f / (float)gw;

    // ---- patch bounds (same fp expressions as per-sample coords) ----
    float ymin = y1 + 0.5f * bin_h * inv_gh;
    float ymax = y1 + 6 * bin_h + ((gh - 1) + 0.5f) * bin_h * inv_gh;
    float xmin = x1 + 0.5f * bin_w * inv_gw;

    int ylo = min((int)fmaxf(ymin, 0.0f), HH - 1);
    int xlo = min((int)fmaxf(xmin, 0.0f), WW - 1);
    int xlo4 = xlo & ~3;               // 16B-aligned patch origin
    int ylmax = min((int)fmaxf(ymax, 0.0f), HH - 1);
    int h_p = min(ylmax + 1, HH - 1) - ylo + 1;   // rows staged, <= 15
    if (h_p > PATCH_H) h_p = PATCH_H;
    // max rel col any sample references: xh <= xlo+14 -> rel <= shift+14 <= 17
    int mcr = min(WW - 1 - xlo4, (xlo - xlo4) + 14);

    // ---- block-uniform ints -> SGPRs (cheapens all downstream addr math) ----
    int s_b   = __builtin_amdgcn_readfirstlane(b);
    int s_ylo = __builtin_amdgcn_readfirstlane(ylo);
    int s_x4  = __builtin_amdgcn_readfirstlane(xlo4);
    int s_hp  = __builtin_amdgcn_readfirstlane(h_p);
    int s_mcr = __builtin_amdgcn_readfirstlane(mcr);
    int s_ns  = __builtin_amdgcn_readfirstlane(gh * gw);
    int ghm   = __builtin_amdgcn_readfirstlane(gh - 1);   // 0 or 1

    // ---- separable per-thread sample precompute ----
    int p  = t & 63;
    int pc = min(p, 48);
    int pw = pc % POOLED;
    int ph = pc / POOLED;
    int cg = t >> 6;                   // wave id = 4-channel group within chunk

    float yb = y1 + ph * bin_h;
    float xb = x1 + pw * bin_w;

    float hy0, ly0, hy1, ly1;          // validity-folded axis weights
    int   ryT0, ryhT0, ryT1, ryhT1;    // dword offsets ry*ROWSTR
    float hx0, lx0, hx1, lx1;
    int   rxT0, rxhT0, rxT1, rxhT1;    // dword offsets rx*CHPAD

#define YSIDE(IYC, HY, LY, RT, RHT) {                                   \
        float y = yb + IYC * bin_h * inv_gh;                            \
        bool vld = (y >= -1.0f) && (y <= (float)HH);                    \
        float yc = fmaxf(y, 0.0f);                                      \
        int yl = min((int)yc, HH - 1);                                  \
        int yh2 = min(yl + 1, HH - 1);                                  \
        float ly = (yl >= HH - 1) ? 0.0f : (yc - (float)yl);            \
        HY = vld ? (1.0f - ly) : 0.0f;                                  \
        LY = vld ? ly : 0.0f;                                           \
        int ry  = max(0, min(yl  - s_ylo, s_hp - 1));                   \
        int ryh = max(0, min(yh2 - s_ylo, s_hp - 1));                   \
        RT  = ry  * ROWSTR;                                             \
        RHT = ryh * ROWSTR;                                             \
    }
#define XSIDE(IXC, HX, LX, RT, RHT) {                                   \
        float x = xb + IXC * bin_w * inv_gw;                            \
        bool vld = (x >= -1.0f) && (x <= (float)WW);                    \
        float xc = fmaxf(x, 0.0f);                                      \
        int xl = min((int)xc, WW - 1);                                  \
        int xh2 = min(xl + 1, WW - 1);                                  \
        float lx = (xl >= WW - 1) ? 0.0f : (xc - (float)xl);            \
        HX = vld ? (1.0f - lx) : 0.0f;                                  \
        LX = vld ? lx : 0.0f;                                           \
        int rxl = max(0, min(xl  - s_x4, PIXROW - 1));                  \
        int rxh = max(0, min(xh2 - s_x4, PIXROW - 1));                  \
        RT  = rxl * CHPAD;                                              \
        RHT = rxh * CHPAD;                                              \
    }
    YSIDE(0.5f, hy0, ly0, ryT0, ryhT0)
    YSIDE(1.5f, hy1, ly1, ryT1, ryhT1)   // read only when gh==2
    XSIDE(0.5f, hx0, lx0, rxT0, rxhT0)
    XSIDE(1.5f, hx1, lx1, rxT1, rxhT1)   // read only when gw==2
#undef YSIDE
#undef XSIDE

    // combine into static sample slots; s enumerates (iy fastest): iy=s%gh, ix=s/gh
    float wa[4], wb[4], wc_[4], wd[4];
    int   oa[4], ob[4], oc[4], od[4];
    // s=0: (0,0)
    wa[0] = hy0 * hx0; wb[0] = hy0 * lx0; wc_[0] = ly0 * hx0; wd[0] = ly0 * lx0;
    oa[0] = ryT0 + rxT0;  ob[0] = ryT0 + rxhT0;
    oc[0] = ryhT0 + rxT0; od[0] = ryhT0 + rxhT0;
    // s=1: (iy,ix) = (ghm, 1-ghm) -> selects
    {
        float hyS = ghm ? hy1 : hy0, lyS = ghm ? ly1 : ly0;
        int ryS = ghm ? ryT1 : ryT0, ryhS = ghm ? ryhT1 : ryhT0;
        float hxS = ghm ? hx0 : hx1, lxS = ghm ? lx0 : lx1;
        int rxS = ghm ? rxT0 : rxT1, rxhS = ghm ? rxhT0 : rxhT1;
        wa[1] = hyS * hxS; wb[1] = hyS * lxS; wc_[1] = lyS * hxS; wd[1] = lyS * lxS;
        oa[1] = ryS + rxS;  ob[1] = ryS + rxhS;
        oc[1] = ryhS + rxS; od[1] = ryhS + rxhS;
    }
    // s=2: (0,1)   (s>=2 implies gh=gw=2)
    wa[2] = hy0 * hx1; wb[2] = hy0 * lx1; wc_[2] = ly0 * hx1; wd[2] = ly0 * lx1;
    oa[2] = ryT0 + rxT1;  ob[2] = ryT0 + rxhT1;
    oc[2] = ryhT0 + rxT1; od[2] = ryhT0 + rxhT1;
    // s=3: (1,1)
    wa[3] = hy1 * hx1; wb[3] = hy1 * lx1; wc_[3] = ly1 * hx1; wd[3] = ly1 * lx1;
    oa[3] = ryT1 + rxT1;  ob[3] = ryT1 + rxhT1;
    oc[3] = ryhT1 + rxT1; od[3] = ryhT1 + rxhT1;

    // ---- staging mapping: one float4 per (lch, row, col-group) slot ----
    int lch = t >> 4;                  // 0..15 channel within chunk
    int sub = t & 15;
    int lim = s_hp * NV;
    const float* gch0 = feat + (s_b * CCH + cb + lch) * HW;

    bool act[NV], actw[NV];
    int  goff[NV];                     // float offset within channel plane
    int  la[NV];                       // LDS float index of col j=0
#pragma unroll
    for (int i = 0; i < NV; ++i) {
        int idx = i * 16 + sub;        // 0..79, each (r,v) pair exactly once
        int r = idx / NV;
        int v = idx - r * NV;
        act[i]  = (idx < lim) && (4 * v <= s_mcr);
        actw[i] = act[i] && (v < 4);   // rc 19 would alias next row -> skip .w on v=4
        goff[i] = (s_ylo + r) * WW + min(s_x4 + 4 * v, WW - 4);
        la[i]   = (r * PIXROW + 4 * v) * CHPAD + lch;
    }

    float sc = inv_gh * inv_gw;

    // ---- chunk 0: load -> write ----
    float4 u0[NV];
#pragma unroll
    for (int i = 0; i < NV; ++i)
        if (act[i]) u0[i] = *(const float4*)(gch0 + goff[i]);
#pragma unroll
    for (int i = 0; i < NV; ++i)
        if (act[i]) {
            float* lp = patch + la[i];
            lp[0]         = u0[i].x;
            lp[CHPAD]     = u0[i].y;
            lp[2 * CHPAD] = u0[i].z;
            if (actw[i]) lp[3 * CHPAD] = u0[i].w;
        }

    // ---- issue chunk-1 loads before the barrier; latency hides under compute 0 ----
    const float* gch1 = gch0 + NCH * HW;
    float4 u1[NV];
#pragma unroll
    for (int i = 0; i < NV; ++i)
        if (act[i]) u1[i] = *(const float4*)(gch1 + goff[i]);

    __syncthreads();

#define BILIN(S) {                                                      \
        float4 va = *(const float4*)(cp + oa[S]);                       \
        float4 vb = *(const float4*)(cp + ob[S]);                       \
        float4 vc = *(const float4*)(cp + oc[S]);                       \
        float4 vd = *(const float4*)(cp + od[S]);                       \
        float w1 = wa[S], w2 = wb[S], w3 = wc_[S], w4 = wd[S];          \
        acc.x += w1 * va.x + w2 * vb.x + w3 * vc.x + w4 * vd.x;         \
        acc.y += w1 * va.y + w2 * vb.y + w3 * vc.y + w4 * vd.y;         \
        acc.z += w1 * va.z + w2 * vb.z + w3 * vc.z + w4 * vd.z;         \
        acc.w += w1 * va.w + w2 * vb.w + w3 * vc.w + w4 * vd.w;         \
    }
#define COMPUTE(CHB) {                                                  \
        float4 acc = {0.0f, 0.0f, 0.0f, 0.0f};                          \
        const float* cp = patch + cg * 4;                               \
        BILIN(0)                                                        \
        if (s_ns > 1) BILIN(1)                                          \
        if (s_ns > 2) { BILIN(2) BILIN(3) }                             \
        int ob_ = (k * CCH + cb + (CHB) + cg * 4) * 49 + p;             \
        out[ob_]          = acc.x * sc;                                 \
        out[ob_ + 49]     = acc.y * sc;                                 \
        out[ob_ + 2 * 49] = acc.z * sc;                                 \
        out[ob_ + 3 * 49] = acc.w * sc;                                 \
    }

    // ---- compute chunk 0 ----
    if (p < 49) COMPUTE(0)

    __syncthreads();                   // WAR: compute 0 done before overwrite

    // ---- chunk 1: write (loads already in flight) ----
#pragma unroll
    for (int i = 0; i < NV; ++i)
        if (act[i]) {
            float* lp = patch + la[i];
            lp[0]         = u1[i].x;
            lp[CHPAD]     = u1[i].y;
            lp[2 * CHPAD] = u1[i].z;
            if (actw[i]) lp[3 * CHPAD] = u1[i].w;
        }
    __syncthreads();

    // ---- compute chunk 1 ----
    if (p < 49) COMPUTE(NCH)
}

extern "C" void kernel_launch(void* const* d_in, const int* in_sizes, int n_in,
                              void* d_out, int out_size, void* d_ws, size_t ws_size,
                              hipStream_t stream) {
    const float* feat  = (const float*)d_in[0];
    const float* boxes = (const float*)d_in[1];
    float* out = (float*)d_out;

    int K = in_sizes[1] / 5;
    int* perm = nullptr;
    if (d_ws && ws_size >= (size_t)K * sizeof(int)) {
        perm = (int*)d_ws;
        box_sort_kernel<<<1, 1024, 0, stream>>>(boxes, perm, K);
    }
    int blocks = K * NBLK_PER_BOX;     // (box, 32-channel group)
    roi_align_kernel<<<blocks, 256, 0, stream>>>(feat, boxes, out, perm, K);
}